// Round 10
// baseline (1216.789 us; speedup 1.0000x reference)
//
#include <hip/hip_runtime.h>
#include <hip/hip_fp16.h>

typedef _Float16 f16x8 __attribute__((ext_vector_type(8)));
typedef float f32x4 __attribute__((ext_vector_type(4)));
typedef unsigned int u32x4 __attribute__((ext_vector_type(4)));
typedef unsigned int u32x2 __attribute__((ext_vector_type(2)));
typedef unsigned long long u64;

static constexpr int T_SEQ = 512;
static constexpr int BATCH = 64;
static constexpr int HID   = 512;
static constexpr int VOC   = 128;

// ---- fp16 arena element offsets ----
static constexpr int AOFF_EMB  = 0;        // 128*256
static constexpr int AOFF_WXH0 = 32768;    // 512*256
static constexpr int AOFF_WHH0 = 163840;   // 512*512
static constexpr int AOFF_WXH1 = 425984;   // 512*512
static constexpr int AOFF_WHH1 = 688128;   // 512*512
static constexpr int AOFF_WHY  = 950272;   // 128*512
static constexpr int ATOT      = 1015808;

// ---- ws byte offsets (identical to R8-proven layout, 137.3 MB) ----
static constexpr size_t OFF_RING   = 16384;
static constexpr size_t RING_BYTES = 32ull * 4 * 512 * 16;            // 1 MB
static constexpr size_t OFF_HIST   = OFF_RING + RING_BYTES;           // 1,064,960
static constexpr size_t HIST_BYTES = 512ull * 16 * 512 * 16;          // 64 MB
static constexpr size_t OFF_ARENA  = OFF_HIST + HIST_BYTES;           // 68,173,824
static constexpr size_t OFF_XW0    = OFF_ARENA + 2ull * ATOT;         // 70,205,440
static constexpr size_t PLANE_B    = (size_t)T_SEQ * BATCH * HID * 2; // 32 MB
static constexpr size_t OFF_H1A    = OFF_XW0 + PLANE_B;               // 103,759,872

__device__ __forceinline__ unsigned short h2u(_Float16 h) {
  union { _Float16 h; unsigned short u; } c; c.h = h; return c.u;
}
__device__ __forceinline__ _Float16 u2h(unsigned short u) {
  union { unsigned short u; _Float16 h; } c; c.u = u; return c.h;
}
__device__ __forceinline__ float fast_tanh(float x) {
  float e = __expf(2.0f * x);
  return 1.0f - 2.0f * __builtin_amdgcn_rcpf(e + 1.0f);
}

// ---- tagged 16B message primitives (single-transaction data+tag) ----
// Discipline after R9's NaN: at most ONE in-flight tagged set per stream,
// short live ranges, stop-and-wait retries (R8-proven).
__device__ __forceinline__ void store16_sys(u64* addr, u64 data, unsigned tag) {
  u32x4 v;
  v.x = (unsigned)data; v.y = (unsigned)(data >> 32);
  v.z = tag;            v.w = 0u;
  asm volatile("global_store_dwordx4 %0, %1, off sc0 sc1"
               :: "v"(addr), "v"(v) : "memory");
}
__device__ __forceinline__ void issue3x16(const u64* a, const u64* b, const u64* c,
                                          u32x4& v0, u32x4& v1, u32x4& v2) {
  asm volatile("global_load_dwordx4 %0, %3, off sc0 sc1\n\t"
               "global_load_dwordx4 %1, %4, off sc0 sc1\n\t"
               "global_load_dwordx4 %2, %5, off sc0 sc1"
               : "=&v"(v0), "=&v"(v1), "=&v"(v2)
               : "v"(a), "v"(b), "v"(c)
               : "memory");
}
__device__ __forceinline__ void issue4x16(const u64* a, const u64* b, const u64* c,
                                          const u64* d, u32x4& v0, u32x4& v1,
                                          u32x4& v2, u32x4& v3) {
  asm volatile("global_load_dwordx4 %0, %4, off sc0 sc1\n\t"
               "global_load_dwordx4 %1, %5, off sc0 sc1\n\t"
               "global_load_dwordx4 %2, %6, off sc0 sc1\n\t"
               "global_load_dwordx4 %3, %7, off sc0 sc1"
               : "=&v"(v0), "=&v"(v1), "=&v"(v2), "=&v"(v3)
               : "v"(a), "v"(b), "v"(c), "v"(d)
               : "memory");
}
__device__ __forceinline__ void wait3(u32x4& v0, u32x4& v1, u32x4& v2) {
  asm volatile("s_waitcnt vmcnt(0)" : "+v"(v0), "+v"(v1), "+v"(v2) :: "memory");
}
// ring wait with the 4 hist-prefetch loads (issued after) still in flight
__device__ __forceinline__ void wait3_v4(u32x4& v0, u32x4& v1, u32x4& v2) {
  asm volatile("s_waitcnt vmcnt(4)" : "+v"(v0), "+v"(v1), "+v"(v2) :: "memory");
}
// hist wait with our own publish store (issued after) still in flight
__device__ __forceinline__ void wait4_v1(u32x4& v0, u32x4& v1, u32x4& v2, u32x4& v3) {
  asm volatile("s_waitcnt vmcnt(1)" : "+v"(v0), "+v"(v1), "+v"(v2), "+v"(v3) :: "memory");
}
__device__ __forceinline__ void drain_all() {
  asm volatile("s_waitcnt vmcnt(0)" ::: "memory");
}
__device__ __forceinline__ void load3x16_sys(const u64* a, const u64* b, const u64* c,
                                             u32x4& v0, u32x4& v1, u32x4& v2) {
  asm volatile("global_load_dwordx4 %0, %3, off sc0 sc1\n\t"
               "global_load_dwordx4 %1, %4, off sc0 sc1\n\t"
               "global_load_dwordx4 %2, %5, off sc0 sc1\n\t"
               "s_waitcnt vmcnt(0)"
               : "=&v"(v0), "=&v"(v1), "=&v"(v2)
               : "v"(a), "v"(b), "v"(c)
               : "memory");
}
__device__ __forceinline__ void load4x16_sys(const u64* a, const u64* b, const u64* c,
                                             const u64* d, u32x4& v0, u32x4& v1,
                                             u32x4& v2, u32x4& v3) {
  asm volatile("global_load_dwordx4 %0, %4, off sc0 sc1\n\t"
               "global_load_dwordx4 %1, %5, off sc0 sc1\n\t"
               "global_load_dwordx4 %2, %6, off sc0 sc1\n\t"
               "global_load_dwordx4 %3, %7, off sc0 sc1\n\t"
               "s_waitcnt vmcnt(0)"
               : "=&v"(v0), "=&v"(v1), "=&v"(v2), "=&v"(v3)
               : "v"(a), "v"(b), "v"(c), "v"(d)
               : "memory");
}

// fp32 params -> fp16 arena; zero ring+hist (contiguous).
__global__ __launch_bounds__(256) void canon_kernel(
    const float* p0, const float* p1, const float* p2, const float* p3,
    const float* p4, const float* p5, _Float16* __restrict__ dst,
    int* __restrict__ ringhist) {
  const int NZ = (int)((RING_BYTES + HIST_BYTES) / 4);
  for (int i = blockIdx.x * 256 + threadIdx.x; i < NZ; i += gridDim.x * 256)
    ringhist[i] = 0;
  const float* srcs[6] = {p0, p1, p2, p3, p4, p5};
  const int ns[6] = {32768, 131072, 262144, 262144, 262144, 65536};
  for (int i = blockIdx.x * 256 + threadIdx.x; i < ATOT; i += gridDim.x * 256) {
    int off = i, s = 0;
    while (off >= ns[s]) { off -= ns[s]; ++s; }
    dst[i] = (_Float16)srcs[s][off];
  }
}

// xwf0[t][n][b] = emb[x[b,t]][:] . Wxh0[n][:] + bh0[n].  Grid (512, 8) x 256.
__global__ __launch_bounds__(256) void xw0_kernel(
    const int* __restrict__ x, const _Float16* __restrict__ emb,
    const _Float16* __restrict__ Wxh, const float* __restrict__ bh,
    _Float16* __restrict__ xwf) {
  __shared__ _Float16 Bs[64][264];
  const int t = blockIdx.x, n0 = blockIdx.y * 64, tid = threadIdx.x;
#pragma unroll
  for (int rep = 0; rep < 8; ++rep) {
    int flat = rep * 256 + tid;
    int row = flat >> 5, c8 = flat & 31;
    *(f16x8*)&Bs[row][c8 * 8] = *(const f16x8*)&Wxh[(size_t)(n0 + row) * 256 + c8 * 8];
  }
  __syncthreads();
  const int wv = tid >> 6, lane = tid & 63, l15 = lane & 15, quad = lane >> 4;
  const int b = wv * 16 + l15;
  const int idx = x[b * 512 + t];
  f32x4 acc[4];
#pragma unroll
  for (int nt = 0; nt < 4; ++nt) { float bv = bh[n0 + nt * 16 + l15]; acc[nt] = {bv, bv, bv, bv}; }
#pragma unroll
  for (int kc = 0; kc < 8; ++kc) {
    f16x8 a = *(const f16x8*)&emb[(size_t)idx * 256 + kc * 32 + quad * 8];
#pragma unroll
    for (int nt = 0; nt < 4; ++nt) {
      f16x8 bf = *(const f16x8*)&Bs[nt * 16 + l15][kc * 32 + quad * 8];
      acc[nt] = __builtin_amdgcn_mfma_f32_16x16x32_f16(a, bf, acc[nt], 0, 0, 0);
    }
  }
#pragma unroll
  for (int nt = 0; nt < 4; ++nt) {
    unsigned int lo = (unsigned int)h2u((_Float16)acc[nt][0]) |
                      ((unsigned int)h2u((_Float16)acc[nt][1]) << 16);
    unsigned int hi = (unsigned int)h2u((_Float16)acc[nt][2]) |
                      ((unsigned int)h2u((_Float16)acc[nt][3]) << 16);
    u32x2 pk = {lo, hi};
    *(u32x2*)&xwf[(size_t)t * 32768 + (size_t)(n0 + nt * 16 + l15) * 64 + wv * 16 + quad * 4] = pk;
  }
}

// ---- layer-0: R8-proven loop, unchanged.
__device__ __forceinline__ void layer0_loop(
    const _Float16* __restrict__ Whh, const _Float16* __restrict__ xwf,
    u64* __restrict__ hist, _Float16* alds, const int g, const int q, const int tid) {
  u64* aldsu = (u64*)alds;
  const int lane = tid & 63, wv = tid >> 6, l15 = lane & 15, quad = lane >> 4;
  const int n0 = q * 128 + wv * 16;

  u32x4 Bw[16];
#pragma unroll
  for (int i = 0; i < 16; ++i) {
    const int kc = (q * 4 + i) & 15;
    Bw[i] = *(const u32x4*)&Whh[(size_t)(n0 + l15) * 512 + kc * 32 + quad * 8];
  }

  int pquar[3];
  {
    int pi = 0;
    for (int qq = 0; qq < 4; ++qq)
      if (qq != q) pquar[pi++] = qq;
  }

  const _Float16* xwb = xwf + (size_t)(n0 + l15) * 64 + g * 16 + quad * 4;
  u32x2 pfx = *(const u32x2*)xwb;

  for (int t = 0; t < T_SEQ; ++t) {
#pragma unroll
    for (int i = 0; i < 16; ++i) asm volatile("" : "+v"(Bw[i]));

    f32x4 accA, accB = {0.f, 0.f, 0.f, 0.f};
    accA[0] = (float)u2h((unsigned short)(pfx.x & 0xFFFFu));
    accA[1] = (float)u2h((unsigned short)(pfx.x >> 16));
    accA[2] = (float)u2h((unsigned short)(pfx.y & 0xFFFFu));
    accA[3] = (float)u2h((unsigned short)(pfx.y >> 16));
    if (t + 1 < T_SEQ) pfx = *(const u32x2*)(xwb + (size_t)(t + 1) * 32768);

    if (t > 0) {
      const u64* a0 = hist + (((size_t)(t - 1) * 16 + g * 4 + pquar[0]) * 512 + tid) * 2;
      const u64* a1 = hist + (((size_t)(t - 1) * 16 + g * 4 + pquar[1]) * 512 + tid) * 2;
      const u64* a2 = hist + (((size_t)(t - 1) * 16 + g * 4 + pquar[2]) * 512 + tid) * 2;
      u32x4 r0, r1, r2;
      issue3x16(a0, a1, a2, r0, r1, r2);   // poll #1 under own MFMAs

#pragma unroll
      for (int i = 0; i < 4; ++i) {        // own-quarter chain -> accA
        const int kc = q * 4 + i;
        f16x8 a = *(const f16x8*)&alds[kc * 512 + lane * 8];
        accA = __builtin_amdgcn_mfma_f32_16x16x32_f16(
            a, __builtin_bit_cast(f16x8, Bw[i]), accA, 0, 0, 0);
      }

      wait3(r0, r1, r2);
      const unsigned wtag = (unsigned)t;
      while ((r0.z != wtag) | (r1.z != wtag) | (r2.z != wtag))
        load3x16_sys(a0, a1, a2, r0, r1, r2);

      aldsu[pquar[0] * 512 + tid] = ((u64)r0.y << 32) | r0.x;
      aldsu[pquar[1] * 512 + tid] = ((u64)r1.y << 32) | r1.x;
      aldsu[pquar[2] * 512 + tid] = ((u64)r2.y << 32) | r2.x;
      __syncthreads();  // bar_A

#pragma unroll
      for (int i = 4; i < 16; ++i) {
        const int kc = (q * 4 + i) & 15;
        f16x8 a = *(const f16x8*)&alds[kc * 512 + lane * 8];
        if (i & 1)
          accB = __builtin_amdgcn_mfma_f32_16x16x32_f16(
              a, __builtin_bit_cast(f16x8, Bw[i]), accB, 0, 0, 0);
        else
          accA = __builtin_amdgcn_mfma_f32_16x16x32_f16(
              a, __builtin_bit_cast(f16x8, Bw[i]), accA, 0, 0, 0);
      }
      __syncthreads();  // bar1
    }

    {
      f32x4 s = accA + accB;
      const int n = n0 + l15;
      const int kc = n >> 5, qd = (n >> 3) & 3, j = n & 7;
#pragma unroll
      for (int r = 0; r < 4; ++r)
        alds[kc * 512 + (qd * 16 + quad * 4 + r) * 8 + j] = (_Float16)fast_tanh(s[r]);
    }
    // intra-wave transpose complete -> publish BEFORE the block barrier
    asm volatile("s_waitcnt lgkmcnt(0)" ::: "memory");
    __builtin_amdgcn_sched_barrier(0);
    {
      u64 msg = aldsu[q * 512 + tid];
      store16_sys(hist + (((size_t)t * 16 + g * 4 + q) * 512 + tid) * 2,
                  msg, (unsigned)(t + 1));
    }
    __syncthreads();    // bar2
  }
}

// ---- layer-1: fused xw1 + recurrence; hist[u+1] PREFETCHED into a
// double-buffered xlds, removing bar_X + hist wait from the critical path.
// Steady state: L1 trails L0 by >=1 step, so the prefetch tag-check is
// first-try; early steps self-throttle via bounded stop-and-wait retry.
__device__ __forceinline__ void layer1_loop(
    const _Float16* __restrict__ Whh, const _Float16* __restrict__ Wxh,
    const float* __restrict__ bh, const u64* __restrict__ hist,
    u64* __restrict__ ring, _Float16* __restrict__ h1A,
    _Float16* alds, _Float16* xlds, const int g, const int q, const int tid) {
  u64* aldsu = (u64*)alds;
  u64* xldsu = (u64*)xlds;              // 2 buffers x 2048 u64 (8192 f16 each)
  const int lane = tid & 63, wv = tid >> 6, l15 = lane & 15, quad = lane >> 4;
  const int n0 = q * 128 + wv * 16;

  u32x4 Bh[16], Bx[16];
#pragma unroll
  for (int i = 0; i < 16; ++i) {
    const int kc = (q * 4 + i) & 15;
    Bh[i] = *(const u32x4*)&Whh[(size_t)(n0 + l15) * 512 + kc * 32 + quad * 8];
  }
#pragma unroll
  for (int i = 0; i < 16; ++i)
    Bx[i] = *(const u32x4*)&Wxh[(size_t)(n0 + l15) * 512 + i * 32 + quad * 8];
  const float bv = bh[n0 + l15];

  u64* pring[3];
  int pquar[3];
  {
    int pi = 0;
    for (int qq = 0; qq < 4; ++qq)
      if (qq != q) { pring[pi] = ring + (size_t)(16 + g * 4 + qq) * 4096; pquar[pi] = qq; ++pi; }
  }
  u64* myring = ring + (size_t)(16 + g * 4 + q) * 4096;

  // prologue: stage hist[0] (tag 1) into buffer 0
  {
    const u64* hb = hist + ((size_t)(g * 4) * 512 + tid) * 2;
    u32x4 hv0, hv1, hv2, hv3;
    load4x16_sys(hb, hb + 1024, hb + 2048, hb + 3072, hv0, hv1, hv2, hv3);
    while (__any((hv0.z != 1u) | (hv1.z != 1u) | (hv2.z != 1u) | (hv3.z != 1u)))
      load4x16_sys(hb, hb + 1024, hb + 2048, hb + 3072, hv0, hv1, hv2, hv3);
    xldsu[0 * 512 + tid] = ((u64)hv0.y << 32) | hv0.x;
    xldsu[1 * 512 + tid] = ((u64)hv1.y << 32) | hv1.x;
    xldsu[2 * 512 + tid] = ((u64)hv2.y << 32) | hv2.x;
    xldsu[3 * 512 + tid] = ((u64)hv3.y << 32) | hv3.x;
  }
  __syncthreads();

  int cur = 0;
  for (int u = 0; u < T_SEQ; ++u) {
#pragma unroll
    for (int i = 0; i < 16; ++i) asm volatile("" : "+v"(Bh[i]));
#pragma unroll
    for (int i = 0; i < 16; ++i) asm volatile("" : "+v"(Bx[i]));

    f32x4 accA = {bv, bv, bv, bv};
    f32x4 accB = {0.f, 0.f, 0.f, 0.f}, accC = {0.f, 0.f, 0.f, 0.f},
          accD = {0.f, 0.f, 0.f, 0.f};

    const int slot = (u - 1) & 3;
    const u64* a0 = pring[0] + (size_t)slot * 1024 + tid * 2;
    const u64* a1 = pring[1] + (size_t)slot * 1024 + tid * 2;
    const u64* a2 = pring[2] + (size_t)slot * 1024 + tid * 2;
    u32x4 r0, r1, r2, hv0, hv1, hv2, hv3;

    if (u > 0) issue3x16(a0, a1, a2, r0, r1, r2);   // ring first (vmcnt FIFO)

    // hist[u+1] prefetch (address clamped on last iter; stage skipped there)
    const int un = (u + 1 < T_SEQ) ? (u + 1) : (T_SEQ - 1);
    const u64* hb = hist + ((size_t)(un * 16 + g * 4) * 512 + tid) * 2;
    issue4x16(hb, hb + 1024, hb + 2048, hb + 3072, hv0, hv1, hv2, hv3);

    if (u > 0) {
#pragma unroll
      for (int i = 0; i < 4; ++i) {                 // own-quarter Whh -> accA
        const int kc = q * 4 + i;
        f16x8 a = *(const f16x8*)&alds[kc * 512 + lane * 8];
        accA = __builtin_amdgcn_mfma_f32_16x16x32_f16(
            a, __builtin_bit_cast(f16x8, Bh[i]), accA, 0, 0, 0);
      }
    }
    // xw1 from the CURRENT buffer — staged last iteration, covered by bar2.
    {
      const _Float16* xb = xlds + cur * 8192;
#pragma unroll
      for (int kc = 0; kc < 16; ++kc) {
        f16x8 a = *(const f16x8*)&xb[kc * 512 + lane * 8];
        if (kc < 8)
          accB = __builtin_amdgcn_mfma_f32_16x16x32_f16(
              a, __builtin_bit_cast(f16x8, Bx[kc]), accB, 0, 0, 0);
        else
          accC = __builtin_amdgcn_mfma_f32_16x16x32_f16(
              a, __builtin_bit_cast(f16x8, Bx[kc]), accC, 0, 0, 0);
      }
    }

    u64 v0 = 0, v1 = 0, v2 = 0;
    if (u > 0) {
      wait3_v4(r0, r1, r2);        // ring landed; 4 hist loads still in flight
      const unsigned wtag = (unsigned)u;
      while ((r0.z != wtag) | (r1.z != wtag) | (r2.z != wtag))
        load3x16_sys(a0, a1, a2, r0, r1, r2);   // drains hist too (harmless)
      v0 = ((u64)r0.y << 32) | r0.x;
      v1 = ((u64)r1.y << 32) | r1.x;
      v2 = ((u64)r2.y << 32) | r2.x;
      aldsu[pquar[0] * 512 + tid] = v0;
      aldsu[pquar[1] * 512 + tid] = v1;
      aldsu[pquar[2] * 512 + tid] = v2;
      __syncthreads();  // bar_A

#pragma unroll
      for (int i = 4; i < 16; ++i) {            // partner Whh, 2 chains (A/D)
        const int kc = (q * 4 + i) & 15;
        f16x8 a = *(const f16x8*)&alds[kc * 512 + lane * 8];
        if (i & 1)
          accD = __builtin_amdgcn_mfma_f32_16x16x32_f16(
              a, __builtin_bit_cast(f16x8, Bh[i]), accD, 0, 0, 0);
        else
          accA = __builtin_amdgcn_mfma_f32_16x16x32_f16(
              a, __builtin_bit_cast(f16x8, Bh[i]), accA, 0, 0, 0);
      }
      if (q == 0) {   // partner-quarter h1A dump, off the detect path
        u64* dplane = (u64*)h1A + ((size_t)(u - 1) * 4 + g) * 2048;
        dplane[pquar[0] * 512 + tid] = v0;
        dplane[pquar[1] * 512 + tid] = v1;
        dplane[pquar[2] * 512 + tid] = v2;
      }
    }
    __syncthreads();    // bar1: all alds/xlds reads done before overwrite
    u64 msg;
    {
      f32x4 s = (accA + accD) + (accB + accC);
      const int n = n0 + l15;
      const int kc = n >> 5, qd = (n >> 3) & 3, j = n & 7;
#pragma unroll
      for (int r = 0; r < 4; ++r)
        alds[kc * 512 + (qd * 16 + quad * 4 + r) * 8 + j] = (_Float16)fast_tanh(s[r]);
    }
    asm volatile("s_waitcnt lgkmcnt(0)" ::: "memory");
    __builtin_amdgcn_sched_barrier(0);
    msg = aldsu[q * 512 + tid];
    store16_sys(myring + (size_t)(u & 3) * 1024 + tid * 2, msg, (unsigned)(u + 1));

    // stage hist[u+1] (tag u+2) into the other buffer; skip on last iter.
    if (u + 1 < T_SEQ) {
      wait4_v1(hv0, hv1, hv2, hv3);   // hist landed; our publish still in flight
      const unsigned ht = (unsigned)(u + 2);
      if (__any((hv0.z != ht) | (hv1.z != ht) | (hv2.z != ht) | (hv3.z != ht))) {
        do {
          load4x16_sys(hb, hb + 1024, hb + 2048, hb + 3072, hv0, hv1, hv2, hv3);
        } while (__any((hv0.z != ht) | (hv1.z != ht) |
                       (hv2.z != ht) | (hv3.z != ht)));
      }
      u64* xn = xldsu + (cur ^ 1) * 2048;
      xn[0 * 512 + tid] = ((u64)hv0.y << 32) | hv0.x;
      xn[1 * 512 + tid] = ((u64)hv1.y << 32) | hv1.x;
      xn[2 * 512 + tid] = ((u64)hv2.y << 32) | hv2.x;
      xn[3 * 512 + tid] = ((u64)hv3.y << 32) | hv3.x;
    }
    if (q == 0)     // own quarter of h1[u] straight from the message
      ((u64*)h1A)[((size_t)u * 4 + g) * 2048 + tid] = msg;
    __syncthreads();    // bar2: alds A-plane + xlds[next] visible
    cur ^= 1;
  }
  drain_all();

  // epilogue: q0 collects partners' h1[511]
  if (q == 0) {
    const int slot = (T_SEQ - 1) & 3;
    const u64* a0 = pring[0] + (size_t)slot * 1024 + tid * 2;
    const u64* a1 = pring[1] + (size_t)slot * 1024 + tid * 2;
    const u64* a2 = pring[2] + (size_t)slot * 1024 + tid * 2;
    u32x4 r0, r1, r2;
    load3x16_sys(a0, a1, a2, r0, r1, r2);
    const unsigned wtag = (unsigned)T_SEQ;
    while ((r0.z != wtag) | (r1.z != wtag) | (r2.z != wtag))
      load3x16_sys(a0, a1, a2, r0, r1, r2);
    u64* dplane = (u64*)h1A + ((size_t)(T_SEQ - 1) * 4 + g) * 2048;
    dplane[pquar[0] * 512 + tid] = ((u64)r0.y << 32) | r0.x;
    dplane[pquar[1] * 512 + tid] = ((u64)r1.y << 32) | r1.x;
    dplane[pquar[2] * 512 + tid] = ((u64)r2.y << 32) | r2.x;
  }
}

// Fused two-layer recurrence: 32 blocks on 256 CUs -> one block per CU.
// lb(512,1) = 256-VGPR cap (R7 lesson: (512,2)'s 128 cap is infeasible).
__global__ __launch_bounds__(512, 1) void rnn_fused_kernel(
    const _Float16* __restrict__ Whh0, const _Float16* __restrict__ xwf0,
    const _Float16* __restrict__ Whh1, const _Float16* __restrict__ Wxh1,
    const float* __restrict__ bh1,
    u64* __restrict__ ring, u64* __restrict__ hist, _Float16* __restrict__ h1A) {
  __shared__ _Float16 lds[24576];   // L0: 16KB alds. L1: 16KB alds + 32KB xlds dbuf.
  const int bid = blockIdx.x, tid = threadIdx.x;
  if (bid < 16) {
    layer0_loop(Whh0, xwf0, hist, lds, bid & 3, bid >> 2, tid);
  } else {
    const int b = bid - 16;
    layer1_loop(Whh1, Wxh1, bh1, hist, ring, h1A, lds, lds + 8192,
                b & 3, b >> 2, tid);
  }
}

// logits[b][t][v] = h1[t,b][:] . Why[v][:] + by[v]; h1 in A-frag layout. Grid 512 x 256.
__global__ __launch_bounds__(256) void logits_kernel(
    const _Float16* __restrict__ h1A, const _Float16* __restrict__ Why,
    const float* __restrict__ by, float* __restrict__ out) {
  const int t = blockIdx.x;
  const int wv = threadIdx.x >> 6, lane = threadIdx.x & 63;
  const int l15 = lane & 15, quad = lane >> 4, bb = wv * 16;
  f32x4 acc[8];
#pragma unroll
  for (int vt = 0; vt < 8; ++vt) { float bvv = by[vt * 16 + l15]; acc[vt] = {bvv, bvv, bvv, bvv}; }
#pragma unroll
  for (int kc = 0; kc < 16; ++kc) {
    f16x8 a = *(const f16x8*)&h1A[(((size_t)t * 4 + wv) * 16 + kc) * 512 + lane * 8];
#pragma unroll
    for (int vt = 0; vt < 8; ++vt) {
      f16x8 b = *(const f16x8*)&Why[(size_t)(vt * 16 + l15) * 512 + kc * 32 + quad * 8];
      acc[vt] = __builtin_amdgcn_mfma_f32_16x16x32_f16(a, b, acc[vt], 0, 0, 0);
    }
  }
#pragma unroll
  for (int vt = 0; vt < 8; ++vt)
#pragma unroll
    for (int r = 0; r < 4; ++r)
      out[((size_t)(bb + quad * 4 + r) * 512 + t) * 128 + vt * 16 + l15] = acc[vt][r];
}

// h_last: h0 from tagged history (t=511), h1 from h1A plane.
__global__ void hlast_kernel(const u64* __restrict__ hist,
                             const _Float16* __restrict__ h1A,
                             float* __restrict__ out) {
  const size_t LOG = (size_t)BATCH * T_SEQ * VOC;
  const size_t HL = (size_t)BATCH * HID;
  int tid = blockIdx.x * 256 + threadIdx.x;
  if (tid < (int)HL) {
    const int b = tid >> 9, n = tid & 511;
    const int gg = b >> 4, m = b & 15;
    const int kc = n >> 5, qd = (n >> 3) & 3, j = n & 7;
    const int pf = kc * 512 + (qd * 16 + m) * 8 + j;
    const int p = pf >> 2;
    const u64 d = hist[(((size_t)(T_SEQ - 1) * 16 + gg * 4 + (p >> 9)) * 512 + (p & 511)) * 2];
    out[LOG + tid] = (float)u2h((unsigned short)(d >> ((pf & 3) * 16)));
    const size_t idx = (((size_t)(T_SEQ - 1) * 4 + gg) * 16 + kc) * 512 + (qd * 16 + m) * 8 + j;
    out[LOG + HL + tid] = (float)h1A[idx];
  }
}

extern "C" void kernel_launch(void* const* d_in, const int* in_sizes, int n_in,
                              void* d_out, int out_size, void* d_ws, size_t ws_size,
                              hipStream_t stream) {
  const int* x = (const int*)d_in[0];
  float* out = (float*)d_out;
  char* ws = (char*)d_ws;
  u64* ring = (u64*)(ws + OFF_RING);
  u64* hist = (u64*)(ws + OFF_HIST);
  _Float16* arena = (_Float16*)(ws + OFF_ARENA);
  _Float16* xw0f = (_Float16*)(ws + OFF_XW0);
  _Float16* h1A  = (_Float16*)(ws + OFF_H1A);

  canon_kernel<<<512, 256, 0, stream>>>(
      (const float*)d_in[1], (const float*)d_in[2], (const float*)d_in[3],
      (const float*)d_in[5], (const float*)d_in[6], (const float*)d_in[8],
      arena, (int*)ring);

  xw0_kernel<<<dim3(512, 8), 256, 0, stream>>>(
      x, arena + AOFF_EMB, arena + AOFF_WXH0, (const float*)d_in[4], xw0f);

  rnn_fused_kernel<<<32, 512, 0, stream>>>(
      arena + AOFF_WHH0, xw0f,
      arena + AOFF_WHH1, arena + AOFF_WXH1, (const float*)d_in[7],
      ring, hist, h1A);

  logits_kernel<<<512, 256, 0, stream>>>(
      h1A, arena + AOFF_WHY, (const float*)d_in[9], out);

  hlast_kernel<<<(BATCH * HID + 255) / 256, 256, 0, stream>>>(hist, h1A, out);
}